// Round 16
// baseline (2026.231 us; speedup 1.0000x reference)
//
#include <hip/hip_runtime.h>
#include <hip/hip_fp16.h>

#define DIM 64
#define EPS 1e-12f
#define BTILE 2048      // edges per block in bucket pass1 (8 per thread)
#define CAPB 5120       // padded slots per 256-node bucket (mean 4082, sigma 64)
#define LOG2E 1.44269504f
#define THR2 11.5416f   // defer-max threshold in log2 domain (= 8 nats)
#define GPERS 2048      // persistent grid: 8 blocks/CU x 256 CUs

__device__ __forceinline__ float group_sum(float v) {
    #pragma unroll
    for (int off = 16; off; off >>= 1) v += __shfl_xor(v, off, 64);
    return v;
}

__device__ __forceinline__ float fexp2(float x) {
#if defined(__has_builtin) && __has_builtin(__builtin_amdgcn_exp2f)
    return __builtin_amdgcn_exp2f(x);
#else
    float r; asm("v_exp_f32 %0, %1" : "=v"(r) : "v"(x)); return r;
#endif
}

// ---- gfx950 mixed-precision helpers ----
__device__ __forceinline__ unsigned pkmul_h2(unsigned a, unsigned b) {
    __half2 ah = *reinterpret_cast<__half2*>(&a);
    __half2 bh = *reinterpret_cast<__half2*>(&b);
    __half2 c  = __hmul2(ah, bh);
    return *reinterpret_cast<unsigned*>(&c);
}
__device__ __forceinline__ float mix_acc_lo(float acc, unsigned p, float s) {
    asm("v_fma_mix_f32 %0, %1, %2, %0 op_sel:[0,0,0] op_sel_hi:[1,0,0]"
        : "+v"(acc) : "v"(p), "v"(s));
    return acc;
}
__device__ __forceinline__ float mix_acc_hi(float acc, unsigned p, float s) {
    asm("v_fma_mix_f32 %0, %1, %2, %0 op_sel:[1,0,0] op_sel_hi:[1,0,0]"
        : "+v"(acc) : "v"(p), "v"(s));
    return acc;
}
#if defined(__has_builtin)
#if __has_builtin(__builtin_amdgcn_fdot2)
#define HAVE_FDOT2 1
#endif
#endif
__device__ __forceinline__ float dot2u(unsigned a, unsigned b) {
#ifdef HAVE_FDOT2
    typedef _Float16 half2_t __attribute__((ext_vector_type(2)));
    half2_t ah = __builtin_bit_cast(half2_t, a);
    half2_t bh = __builtin_bit_cast(half2_t, b);
    return __builtin_amdgcn_fdot2(ah, bh, 0.f, false);
#else
    float t;
    asm("v_fma_mix_f32 %0, %1, %2, 0 op_sel:[0,0,0] op_sel_hi:[1,1,0]\n\t"
        "v_fma_mix_f32 %0, %1, %2, %0 op_sel:[1,1,0] op_sel_hi:[1,1,0]"
        : "=&v"(t) : "v"(a), "v"(b));
    return t;
#endif
}

// gather one unsigned (2 halves) from fp16 row (packed & ~127) at lane byte gl4
__device__ __forceinline__ unsigned gather_u(const __half* __restrict__ xh,
                                             int pe, int gl4) {
    return *(const unsigned*)((const char*)xh + (pe & 0x7FFF80) + gl4);
}

// pass1: scatter edges into padded bucket-major records; also copies ent -> xh0.
// record = headlow(8) | tail(16)<<8 | rel(5)<<24   (N <= 65536, R <= 32)
__global__ void bucket_pass1(const int* __restrict__ head,
                             const int* __restrict__ tail,
                             const int* __restrict__ etype,
                             int* __restrict__ gcur,          // zeroed, 256 entries
                             int* __restrict__ bbuf,
                             const float4* __restrict__ ent4,
                             ushort4* __restrict__ xh4, int n4, int E) {
    __shared__ int lhist[256], lbase[256], lrun[256];
    int t0 = blockIdx.x * BTILE;
    int tid = threadIdx.x;
    lhist[tid] = 0; lrun[tid] = 0;
    __syncthreads();
    int hreg[8];
    #pragma unroll
    for (int k = 0; k < 8; ++k) {
        int e = t0 + k * 256 + tid;
        hreg[k] = -1;
        if (e < E) { hreg[k] = head[e]; atomicAdd(&lhist[hreg[k] >> 8], 1); }
    }
    __syncthreads();
    {
        int c = lhist[tid];
        lbase[tid] = tid * CAPB + (c ? atomicAdd(&gcur[tid], c) : 0);
    }
    __syncthreads();
    #pragma unroll
    for (int k = 0; k < 8; ++k) {
        int e = t0 + k * 256 + tid;
        if (e < E) {
            int b = hreg[k] >> 8;
            int dst = lbase[b] + atomicAdd(&lrun[b], 1);
            bbuf[dst] = (hreg[k] & 255) | (tail[e] << 8) | ((etype[e] - 1) << 24);
        }
    }
    // merged init: xh0 = fp16(ent), grid-stride
    for (int i = blockIdx.x * 256 + tid; i < n4; i += gridDim.x * 256) {
        float4 v = ent4[i];
        ushort4 b;
        b.x = __half_as_ushort(__float2half(v.x));
        b.y = __half_as_ushort(__float2half(v.y));
        b.z = __half_as_ushort(__float2half(v.z));
        b.w = __half_as_ushort(__float2half(v.w));
        xh4[i] = b;
    }
}

// pass2: per bucket — LDS hist + scan -> rp2 (beg,end), counting sort -> packed
// packed final format: (tail*128) | rel   (byte-offset ready)
__global__ void bucket_pass2(const int* __restrict__ bbuf,
                             const int* __restrict__ gcur,
                             int2* __restrict__ rp2,
                             int* __restrict__ packed, int N) {
    __shared__ int lhist[256], lcur[256], wsum[4], wpre[4];
    __shared__ int stage[CAPB];
    int b = blockIdx.x, tid = threadIdx.x;
    int ebase = b * CAPB;
    int cnt = min(gcur[b], CAPB);
    int n0 = b << 8;
    lhist[tid] = 0;
    __syncthreads();
    for (int i = tid; i < cnt; i += 256)
        atomicAdd(&lhist[bbuf[ebase + i] & 255], 1);
    __syncthreads();
    int c = lhist[tid];
    int lane = tid & 63, wid = tid >> 6;
    int inc = c;
    #pragma unroll
    for (int off = 1; off < 64; off <<= 1) {
        int t = __shfl_up(inc, off, 64);
        if (lane >= off) inc += t;
    }
    if (lane == 63) wsum[wid] = inc;
    __syncthreads();
    if (tid == 0) {
        int a = 0;
        #pragma unroll
        for (int k = 0; k < 4; ++k) { wpre[k] = a; a += wsum[k]; }
    }
    __syncthreads();
    int excl = wpre[wid] + inc - c;
    lcur[tid] = excl;
    int node = n0 + tid;
    if (node < N) rp2[node] = make_int2(ebase + excl, ebase + excl + c);
    __syncthreads();
    for (int i = tid; i < cnt; i += 256) {
        int v = bbuf[ebase + i];
        int pos = atomicAdd(&lcur[v & 255], 1);
        stage[pos] = (((v >> 8) & 0xFFFF) << 7) | ((v >> 24) & 31);
    }
    __syncthreads();
    for (int i = tid; i < cnt; i += 256)
        packed[ebase + i] = stage[i];
}

// Fused: kg scores (log2 domain) + online-weighted hop1 (defer-max) + exp2 finalize.
// PERSISTENT: each wave pulls node ids from a global counter (load balance).
__global__ void fused_score_hop1_kernel(const __half* __restrict__ xh_old,
                                        const float* __restrict__ relemb,
                                        const int2* __restrict__ rp2,
                                        const int* __restrict__ packed,
                                        float* __restrict__ score,
                                        __half* __restrict__ xh_new,
                                        int* __restrict__ nctr, int N, int R) {
    __shared__ unsigned srelh[1024];             // up to 32 relations x 32 half2
    __shared__ __align__(16) int ptile[4][64];   // per-wave packed tile
    for (int i = threadIdx.x; i < R * 32; i += blockDim.x) {
        float2 f = *(const float2*)&relemb[2 * i];
        __half2 h = __floats2half2_rn(f.x, f.y);
        srelh[i] = *reinterpret_cast<unsigned*>(&h);
    }
    __syncthreads();
    int lane = threadIdx.x & 63;
    int wslot = (threadIdx.x >> 6) & 3;
    const int gl = lane & 31;
    const int gl4 = gl << 2;
    const int hi = lane >> 5;
    const bool b4 = lane & 16, b3 = lane & 8;
    for (;;) {
        int w;
        if (lane == 0) w = atomicAdd(nctr, 1);
        w = __shfl(w, 0, 64);
        if (w >= N) break;
        int2 be = rp2[w];
        int beg = be.x, end = be.y;
        if (beg == end) {              // agg=0 -> x=0
            if (hi) *(__half2*)&xh_new[w * DIM + 2 * gl] = __floats2half2_rn(0.f, 0.f);
            continue;
        }
        unsigned ehu = *(const unsigned*)&xh_old[w * DIM + 2 * gl];   // own row
        float m_run = -3.4e38f;        // log2-domain running max
        float accx = 0.f, accy = 0.f;  // scaled by 2^-m_run
        for (int base = beg; base < end; base += 64) {
            int n = min(64, end - base);
            int pv = (lane < n) ? packed[base + lane] : 0;
            ptile[wslot][lane] = pv;   // wave-synchronous LDS stage
            for (int j = 0; j < n; j += 8) {   // 8 edges: 4 slots x 2 groups
                unsigned pu[4];
                float v[4];
                #pragma unroll
                for (int k = 0; k < 4; ++k) {
                    int e0 = j + 2 * k;
                    int2 pq = *(const int2*)&ptile[wslot][e0];   // broadcast read
                    int pe  = hi ? pq.y : pq.x;
                    unsigned gu = gather_u(xh_old, pe, gl4);
                    unsigned ru = srelh[((pe & 127) << 5) + gl];
                    pu[k] = pkmul_h2(ru, gu);          // rel * gathered x (half2)
                    v[k]  = dot2u(pu[k], ehu);
                }
                // slot-split tree reduce over the 32-lane group
                float w0, w1, t;
                {
                    float s0 = __shfl_xor(v[0], 16, 64), s1 = __shfl_xor(v[1], 16, 64);
                    float s2 = __shfl_xor(v[2], 16, 64), s3 = __shfl_xor(v[3], 16, 64);
                    w0 = b4 ? (v[2] + s2) : (v[0] + s0);
                    w1 = b4 ? (v[3] + s3) : (v[1] + s1);
                }
                {
                    float s0 = __shfl_xor(w0, 8, 64), s1 = __shfl_xor(w1, 8, 64);
                    t = b3 ? (w1 + s1) : (w0 + s0);
                }
                t += __shfl_xor(t, 4, 64);
                t += __shfl_xor(t, 2, 64);
                t += __shfl_xor(t, 1, 64);
                float t2 = t * LOG2E;              // log2 domain
                int el = j + 2 * ((lane >> 3) & 3) + hi;
                if (el < n && (lane & 7) == 0) score[base + el] = t2;
                float t0 = __shfl(t2, (lane & 32) +  0, 64);
                float t1 = __shfl(t2, (lane & 32) +  8, 64);
                float t2b = __shfl(t2, (lane & 32) + 16, 64);
                float t3 = __shfl(t2, (lane & 32) + 24, 64);
                bool va0 = (j + 0 + hi) < n, va1 = (j + 2 + hi) < n;
                bool va2 = (j + 4 + hi) < n, va3 = (j + 6 + hi) < n;
                float mnew = m_run;
                if (va0) mnew = fmaxf(mnew, t0);
                if (va1) mnew = fmaxf(mnew, t1);
                if (va2) mnew = fmaxf(mnew, t2b);
                if (va3) mnew = fmaxf(mnew, t3);
                if (mnew - m_run > THR2) {         // defer-max: rare rescale
                    float sc = fexp2(m_run - mnew);
                    accx *= sc; accy *= sc;
                    m_run = mnew;
                }
                float e0w = va0 ? fexp2(t0 - m_run) : 0.f;
                float e1w = va1 ? fexp2(t1 - m_run) : 0.f;
                float e2w = va2 ? fexp2(t2b - m_run) : 0.f;
                float e3w = va3 ? fexp2(t3 - m_run) : 0.f;
                accx = mix_acc_lo(accx, pu[0], e0w);
                accy = mix_acc_hi(accy, pu[0], e0w);
                accx = mix_acc_lo(accx, pu[1], e1w);
                accy = mix_acc_hi(accy, pu[1], e1w);
                accx = mix_acc_lo(accx, pu[2], e2w);
                accy = mix_acc_hi(accy, pu[2], e2w);
                accx = mix_acc_lo(accx, pu[3], e3w);
                accy = mix_acc_hi(accy, pu[3], e3w);
            }
        }
        // combine the two groups under a common basis M (cancels in normalize)
        float mo = __shfl_xor(m_run, 32, 64);
        float M  = fmaxf(m_run, mo);
        float cs = fexp2(m_run - M);
        accx *= cs; accy *= cs;
        accx += __shfl_xor(accx, 32, 64);
        accy += __shfl_xor(accy, 32, 64);
        float s2n = group_sum(accx * accx + accy * accy);
        float inv = 1.0f / fmaxf(sqrtf(s2n), EPS);
        if (hi) *(__half2*)&xh_new[w * DIM + 2 * gl] =
            __floats2half2_rn(accx * inv, accy * inv);
        // finalize for hops 2,3: unnormalized weights exp2(t2 - M), bounded
        for (int i = beg + lane; i < end; i += 64)
            score[i] = fexp2(score[i] - M);
    }
}

// hop2: x2 = norm(sum score*rel*x1[tail]); persistent work-stealing.
__global__ void hop_kernel(const float* __restrict__ relemb,
                           const int2* __restrict__ rp2,
                           const int* __restrict__ packed,
                           const float* __restrict__ score,
                           const __half* __restrict__ xh_old,
                           __half* __restrict__ xh_new,
                           int* __restrict__ nctr, int N, int R) {
    __shared__ unsigned srelh[1024];
    __shared__ __align__(16) int2 tile[4][64];
    for (int i = threadIdx.x; i < R * 32; i += blockDim.x) {
        float2 f = *(const float2*)&relemb[2 * i];
        __half2 h = __floats2half2_rn(f.x, f.y);
        srelh[i] = *reinterpret_cast<unsigned*>(&h);
    }
    __syncthreads();
    int lane = threadIdx.x & 63;
    int wslot = (threadIdx.x >> 6) & 3;
    const int gl = lane & 31;
    const int gl4 = gl << 2;
    const int hi = lane >> 5;
    for (;;) {
        int w;
        if (lane == 0) w = atomicAdd(nctr, 1);
        w = __shfl(w, 0, 64);
        if (w >= N) break;
        int2 be = rp2[w];
        int beg = be.x, end = be.y;
        float accx = 0.f, accy = 0.f;
        for (int base = beg; base < end; base += 64) {
            int n = min(64, end - base);
            int2 ps = make_int2(0, 0);
            if (lane < n) {
                ps.x = packed[base + lane];
                ps.y = __float_as_int(score[base + lane]);
            }
            tile[wslot][lane] = ps;
            for (int j = 0; j < n; j += 16) {
                #pragma unroll
                for (int k = 0; k < 8; ++k) {
                    int e0 = j + 2 * k;
                    int4 q = *(const int4*)&tile[wslot][e0];
                    int   pe = hi ? q.z : q.x;
                    float se = __int_as_float(hi ? q.w : q.y);
                    unsigned gu = gather_u(xh_old, pe, gl4);
                    unsigned ru = srelh[((pe & 127) << 5) + gl];
                    unsigned pu = pkmul_h2(ru, gu);
                    accx = mix_acc_lo(accx, pu, se);
                    accy = mix_acc_hi(accy, pu, se);
                }
            }
        }
        accx += __shfl_xor(accx, 32, 64);
        accy += __shfl_xor(accy, 32, 64);
        float s = group_sum(accx * accx + accy * accy);
        float inv = 1.0f / fmaxf(sqrtf(s), EPS);
        if (hi) *(__half2*)&xh_new[w * DIM + 2 * gl] =
            __floats2half2_rn(accx * inv, accy * inv);
    }
}

// hop3: x3 from x2 gathers; out = ent + x1 + x2 + x3; persistent work-stealing.
__global__ void hop3_kernel(const float* __restrict__ relemb,
                            const int2* __restrict__ rp2,
                            const int* __restrict__ packed,
                            const float* __restrict__ score,
                            const __half* __restrict__ xh2,
                            const __half* __restrict__ xh1,
                            const float* __restrict__ ent,
                            float* __restrict__ out,
                            int* __restrict__ nctr, int N, int R) {
    __shared__ unsigned srelh[1024];
    __shared__ __align__(16) int2 tile[4][64];
    for (int i = threadIdx.x; i < R * 32; i += blockDim.x) {
        float2 f = *(const float2*)&relemb[2 * i];
        __half2 h = __floats2half2_rn(f.x, f.y);
        srelh[i] = *reinterpret_cast<unsigned*>(&h);
    }
    __syncthreads();
    int lane = threadIdx.x & 63;
    int wslot = (threadIdx.x >> 6) & 3;
    const int gl = lane & 31;
    const int gl4 = gl << 2;
    const int hi = lane >> 5;
    for (;;) {
        int w;
        if (lane == 0) w = atomicAdd(nctr, 1);
        w = __shfl(w, 0, 64);
        if (w >= N) break;
        int2 be = rp2[w];
        int beg = be.x, end = be.y;
        float accx = 0.f, accy = 0.f;
        for (int base = beg; base < end; base += 64) {
            int n = min(64, end - base);
            int2 ps = make_int2(0, 0);
            if (lane < n) {
                ps.x = packed[base + lane];
                ps.y = __float_as_int(score[base + lane]);
            }
            tile[wslot][lane] = ps;
            for (int j = 0; j < n; j += 16) {
                #pragma unroll
                for (int k = 0; k < 8; ++k) {
                    int e0 = j + 2 * k;
                    int4 q = *(const int4*)&tile[wslot][e0];
                    int   pe = hi ? q.z : q.x;
                    float se = __int_as_float(hi ? q.w : q.y);
                    unsigned gu = gather_u(xh2, pe, gl4);
                    unsigned ru = srelh[((pe & 127) << 5) + gl];
                    unsigned pu = pkmul_h2(ru, gu);
                    accx = mix_acc_lo(accx, pu, se);
                    accy = mix_acc_hi(accy, pu, se);
                }
            }
        }
        accx += __shfl_xor(accx, 32, 64);
        accy += __shfl_xor(accy, 32, 64);
        float s = group_sum(accx * accx + accy * accy);
        float inv = 1.0f / fmaxf(sqrtf(s), EPS);
        float xn0 = accx * inv, xn1 = accy * inv;
        if (hi == 0) {
            float2 ev = *(const float2*)&ent[w * DIM + 2 * gl];
            float2 f1 = __half22float2(*(const __half2*)&xh1[w * DIM + 2 * gl]);
            float2 f2 = __half22float2(*(const __half2*)&xh2[w * DIM + 2 * gl]);
            float2 o;
            o.x = ev.x + f1.x + f2.x + xn0;
            o.y = ev.y + f1.y + f2.y + xn1;
            *(float2*)&out[w * DIM + 2 * gl] = o;
        }
    }
}

extern "C" void kernel_launch(void* const* d_in, const int* in_sizes, int n_in,
                              void* d_out, int out_size, void* d_ws, size_t ws_size,
                              hipStream_t stream) {
    const float* ent    = (const float*)d_in[0];
    const float* relemb = (const float*)d_in[1];
    const int*   eidx   = (const int*)d_in[2];
    const int*   etype  = (const int*)d_in[3];
    float* out = (float*)d_out;

    const int N = in_sizes[0] / DIM;   // 50000 (<= 65536 for 16-bit tail packing)
    const int R = in_sizes[1] / DIM;   // 20
    const int E = in_sizes[3];         // 800000
    const int* head = eidx;
    const int* tail = eidx + E;

    char* ws = (char*)d_ws;
    size_t off = 0;
    auto alloc = [&](size_t bytes) {
        char* p = ws + off;
        off += (bytes + 255) & ~size_t(255);
        return p;
    };
    int nbk = (N + 255) >> 8;                       // 256-node buckets (196)
    size_t padE = (size_t)nbk * CAPB;               // padded edge space
    int*   gcur   = (int*)alloc(272 * 4);           // 256 cursors + 3 node counters
    int2*  rp2    = (int2*)alloc((size_t)N * 8);
    int*   bbuf   = (int*)alloc(padE * 4);
    int*   packed = (int*)alloc(padE * 4);
    float* score  = (float*)alloc(padE * 4);
    __half* xh0   = (__half*)alloc((size_t)N * DIM * 2);
    __half* xh1   = (__half*)alloc((size_t)N * DIM * 2);
    __half* xh2   = (__half*)alloc((size_t)N * DIM * 2);
    (void)ws_size;
    int* nctr1 = gcur + 256;
    int* nctr2 = gcur + 260;
    int* nctr3 = gcur + 264;

    hipMemsetAsync(gcur, 0, 272 * 4, stream);

    // padded bucket-major CSR: pass1 (scatter + merged ent->fp16 init) -> pass2
    int ebBlocks = (E + BTILE - 1) / BTILE;
    int n4 = N * DIM / 4;
    bucket_pass1<<<ebBlocks, 256, 0, stream>>>(head, tail, etype, gcur, bbuf,
                                               (const float4*)ent, (ushort4*)xh0,
                                               n4, E);
    bucket_pass2<<<nbk, 256, 0, stream>>>(bbuf, gcur, rp2, packed, N);

    // persistent node kernels: 8 blocks/CU, work-stealing via nctr
    fused_score_hop1_kernel<<<GPERS, 256, 0, stream>>>(xh0, relemb, rp2, packed,
                                                       score, xh1, nctr1, N, R);
    hop_kernel<<<GPERS, 256, 0, stream>>>(relemb, rp2, packed, score,
                                          xh1, xh2, nctr2, N, R);
    hop3_kernel<<<GPERS, 256, 0, stream>>>(relemb, rp2, packed, score,
                                           xh2, xh1, ent, out, nctr3, N, R);
}

// Round 17
// 132.176 us; speedup vs baseline: 15.3297x; 15.3297x over previous
//
#include <hip/hip_runtime.h>
#include <hip/hip_fp16.h>

#define DIM 64
#define EPS 1e-12f
#define BTILE 2048      // edges per block in bucket pass1 (8 per thread)
#define CAPB 5120       // padded slots per 256-node bucket (mean 4082, sigma 64)
#define LOG2E 1.44269504f
#define THR2 11.5416f   // defer-max threshold in log2 domain (= 8 nats)

__device__ __forceinline__ float group_sum(float v) {
    #pragma unroll
    for (int off = 16; off; off >>= 1) v += __shfl_xor(v, off, 64);
    return v;
}

__device__ __forceinline__ float fexp2(float x) {
#if defined(__has_builtin) && __has_builtin(__builtin_amdgcn_exp2f)
    return __builtin_amdgcn_exp2f(x);
#else
    float r; asm("v_exp_f32 %0, %1" : "=v"(r) : "v"(x)); return r;
#endif
}

// ---- gfx950 mixed-precision helpers ----
__device__ __forceinline__ unsigned pkmul_h2(unsigned a, unsigned b) {
    __half2 ah = *reinterpret_cast<__half2*>(&a);
    __half2 bh = *reinterpret_cast<__half2*>(&b);
    __half2 c  = __hmul2(ah, bh);
    return *reinterpret_cast<unsigned*>(&c);
}
__device__ __forceinline__ float mix_acc_lo(float acc, unsigned p, float s) {
    asm("v_fma_mix_f32 %0, %1, %2, %0 op_sel:[0,0,0] op_sel_hi:[1,0,0]"
        : "+v"(acc) : "v"(p), "v"(s));
    return acc;
}
__device__ __forceinline__ float mix_acc_hi(float acc, unsigned p, float s) {
    asm("v_fma_mix_f32 %0, %1, %2, %0 op_sel:[1,0,0] op_sel_hi:[1,0,0]"
        : "+v"(acc) : "v"(p), "v"(s));
    return acc;
}
#if defined(__has_builtin)
#if __has_builtin(__builtin_amdgcn_fdot2)
#define HAVE_FDOT2 1
#endif
#endif
__device__ __forceinline__ float dot2u(unsigned a, unsigned b) {
#ifdef HAVE_FDOT2
    typedef _Float16 half2_t __attribute__((ext_vector_type(2)));
    half2_t ah = __builtin_bit_cast(half2_t, a);
    half2_t bh = __builtin_bit_cast(half2_t, b);
    return __builtin_amdgcn_fdot2(ah, bh, 0.f, false);
#else
    float t;
    asm("v_fma_mix_f32 %0, %1, %2, 0 op_sel:[0,0,0] op_sel_hi:[1,1,0]\n\t"
        "v_fma_mix_f32 %0, %1, %2, %0 op_sel:[1,1,0] op_sel_hi:[1,1,0]"
        : "=&v"(t) : "v"(a), "v"(b));
    return t;
#endif
}

// gather one unsigned (2 halves) from fp16 row (packed & ~127) at lane byte gl4
__device__ __forceinline__ unsigned gather_u(const __half* __restrict__ xh,
                                             int pe, int gl4) {
    return *(const unsigned*)((const char*)xh + (pe & 0x7FFF80) + gl4);
}

// pass1: scatter edges into padded bucket-major records; grid-stride tail copies
// ent -> xh0 (merged init, saves a launch).
// record = headlow(8) | tail(16)<<8 | rel(5)<<24   (N <= 65536, R <= 32)
__global__ void bucket_pass1(const int* __restrict__ head,
                             const int* __restrict__ tail,
                             const int* __restrict__ etype,
                             int* __restrict__ gcur,          // zeroed, 256 entries
                             int* __restrict__ bbuf,
                             const float4* __restrict__ ent4,
                             ushort4* __restrict__ xh4, int n4, int E) {
    __shared__ int lhist[256], lbase[256], lrun[256];
    int t0 = blockIdx.x * BTILE;
    int tid = threadIdx.x;
    lhist[tid] = 0; lrun[tid] = 0;
    __syncthreads();
    int hreg[8];
    #pragma unroll
    for (int k = 0; k < 8; ++k) {
        int e = t0 + k * 256 + tid;
        hreg[k] = -1;
        if (e < E) { hreg[k] = head[e]; atomicAdd(&lhist[hreg[k] >> 8], 1); }
    }
    __syncthreads();
    {
        int c = lhist[tid];
        lbase[tid] = tid * CAPB + (c ? atomicAdd(&gcur[tid], c) : 0);
    }
    __syncthreads();
    #pragma unroll
    for (int k = 0; k < 8; ++k) {
        int e = t0 + k * 256 + tid;
        if (e < E) {
            int b = hreg[k] >> 8;
            int dst = lbase[b] + atomicAdd(&lrun[b], 1);
            bbuf[dst] = (hreg[k] & 255) | (tail[e] << 8) | ((etype[e] - 1) << 24);
        }
    }
    // merged init: xh0 = fp16(ent), grid-stride
    for (int i = blockIdx.x * 256 + tid; i < n4; i += gridDim.x * 256) {
        float4 v = ent4[i];
        ushort4 b;
        b.x = __half_as_ushort(__float2half(v.x));
        b.y = __half_as_ushort(__float2half(v.y));
        b.z = __half_as_ushort(__float2half(v.z));
        b.w = __half_as_ushort(__float2half(v.w));
        xh4[i] = b;
    }
}

// pass2: per bucket — LDS hist + scan -> rp2 (beg,end), counting sort -> packed
// packed final format: (tail*128) | rel   (byte-offset ready)
__global__ void bucket_pass2(const int* __restrict__ bbuf,
                             const int* __restrict__ gcur,
                             int2* __restrict__ rp2,
                             int* __restrict__ packed, int N) {
    __shared__ int lhist[256], lcur[256], wsum[4], wpre[4];
    __shared__ int stage[CAPB];
    int b = blockIdx.x, tid = threadIdx.x;
    int ebase = b * CAPB;
    int cnt = min(gcur[b], CAPB);
    int n0 = b << 8;
    lhist[tid] = 0;
    __syncthreads();
    for (int i = tid; i < cnt; i += 256)
        atomicAdd(&lhist[bbuf[ebase + i] & 255], 1);
    __syncthreads();
    int c = lhist[tid];
    int lane = tid & 63, wid = tid >> 6;
    int inc = c;
    #pragma unroll
    for (int off = 1; off < 64; off <<= 1) {
        int t = __shfl_up(inc, off, 64);
        if (lane >= off) inc += t;
    }
    if (lane == 63) wsum[wid] = inc;
    __syncthreads();
    if (tid == 0) {
        int a = 0;
        #pragma unroll
        for (int k = 0; k < 4; ++k) { wpre[k] = a; a += wsum[k]; }
    }
    __syncthreads();
    int excl = wpre[wid] + inc - c;
    lcur[tid] = excl;
    int node = n0 + tid;
    if (node < N) rp2[node] = make_int2(ebase + excl, ebase + excl + c);
    __syncthreads();
    for (int i = tid; i < cnt; i += 256) {
        int v = bbuf[ebase + i];
        int pos = atomicAdd(&lcur[v & 255], 1);
        stage[pos] = (((v >> 8) & 0xFFFF) << 7) | ((v >> 24) & 31);
    }
    __syncthreads();
    for (int i = tid; i < cnt; i += 256)
        packed[ebase + i] = stage[i];
}

// Fused: kg scores (log2 domain) + online-weighted hop1 (defer-max) + exp2 finalize.
// Scores for hops 2,3 are UNNORMALIZED exp2(t2 - M2): per-node factor cancels in
// the hop's L2-normalize.
__global__ void fused_score_hop1_kernel(const __half* __restrict__ xh_old,
                                        const float* __restrict__ relemb,
                                        const int2* __restrict__ rp2,
                                        const int* __restrict__ packed,
                                        float* __restrict__ score,
                                        __half* __restrict__ xh_new, int N, int R) {
    __shared__ unsigned srelh[1024];             // up to 32 relations x 32 half2
    __shared__ __align__(16) int ptile[4][64];   // per-wave packed tile
    for (int i = threadIdx.x; i < R * 32; i += blockDim.x) {
        float2 f = *(const float2*)&relemb[2 * i];
        __half2 h = __floats2half2_rn(f.x, f.y);
        srelh[i] = *reinterpret_cast<unsigned*>(&h);
    }
    __syncthreads();
    int w    = (blockIdx.x * blockDim.x + threadIdx.x) >> 6;
    int lane = threadIdx.x & 63;
    int wslot = (threadIdx.x >> 6) & 3;
    if (w >= N) return;
    int2 be = rp2[w];
    int beg = be.x, end = be.y;
    const int gl = lane & 31;
    const int gl4 = gl << 2;
    const int hi = lane >> 5;
    if (beg == end) {              // agg=0 -> x=0
        if (hi) *(__half2*)&xh_new[w * DIM + 2 * gl] = __floats2half2_rn(0.f, 0.f);
        return;
    }
    const bool b4 = lane & 16, b3 = lane & 8;
    unsigned ehu = *(const unsigned*)&xh_old[w * DIM + 2 * gl];   // own row (fp16)
    float m_run = -3.4e38f;        // log2-domain running max
    float accx = 0.f, accy = 0.f;  // scaled by 2^-m_run
    for (int base = beg; base < end; base += 64) {
        int n = min(64, end - base);
        int pv = (lane < n) ? packed[base + lane] : 0;
        ptile[wslot][lane] = pv;   // wave-synchronous LDS stage
        for (int j = 0; j < n; j += 8) {   // 8 edges: 4 slots x 2 groups
            unsigned pu[4];
            float v[4];
            #pragma unroll
            for (int k = 0; k < 4; ++k) {
                int e0 = j + 2 * k;
                int2 pq = *(const int2*)&ptile[wslot][e0];   // broadcast read
                int pe  = hi ? pq.y : pq.x;
                unsigned gu = gather_u(xh_old, pe, gl4);
                unsigned ru = srelh[((pe & 127) << 5) + gl];
                pu[k] = pkmul_h2(ru, gu);          // rel * gathered x (half2)
                v[k]  = dot2u(pu[k], ehu);
            }
            // slot-split tree reduce over the 32-lane group
            float w0, w1, t;
            {
                float s0 = __shfl_xor(v[0], 16, 64), s1 = __shfl_xor(v[1], 16, 64);
                float s2 = __shfl_xor(v[2], 16, 64), s3 = __shfl_xor(v[3], 16, 64);
                w0 = b4 ? (v[2] + s2) : (v[0] + s0);
                w1 = b4 ? (v[3] + s3) : (v[1] + s1);
            }
            {
                float s0 = __shfl_xor(w0, 8, 64), s1 = __shfl_xor(w1, 8, 64);
                t = b3 ? (w1 + s1) : (w0 + s0);
            }
            t += __shfl_xor(t, 4, 64);
            t += __shfl_xor(t, 2, 64);
            t += __shfl_xor(t, 1, 64);
            float t2 = t * LOG2E;              // log2 domain
            int el = j + 2 * ((lane >> 3) & 3) + hi;
            if (el < n && (lane & 7) == 0) score[base + el] = t2;
            float t0 = __shfl(t2, (lane & 32) +  0, 64);
            float t1 = __shfl(t2, (lane & 32) +  8, 64);
            float t2b = __shfl(t2, (lane & 32) + 16, 64);
            float t3 = __shfl(t2, (lane & 32) + 24, 64);
            bool va0 = (j + 0 + hi) < n, va1 = (j + 2 + hi) < n;
            bool va2 = (j + 4 + hi) < n, va3 = (j + 6 + hi) < n;
            float mnew = m_run;
            if (va0) mnew = fmaxf(mnew, t0);
            if (va1) mnew = fmaxf(mnew, t1);
            if (va2) mnew = fmaxf(mnew, t2b);
            if (va3) mnew = fmaxf(mnew, t3);
            if (mnew - m_run > THR2) {         // defer-max: rare rescale
                float sc = fexp2(m_run - mnew);
                accx *= sc; accy *= sc;
                m_run = mnew;
            }
            float e0w = va0 ? fexp2(t0 - m_run) : 0.f;
            float e1w = va1 ? fexp2(t1 - m_run) : 0.f;
            float e2w = va2 ? fexp2(t2b - m_run) : 0.f;
            float e3w = va3 ? fexp2(t3 - m_run) : 0.f;
            accx = mix_acc_lo(accx, pu[0], e0w);
            accy = mix_acc_hi(accy, pu[0], e0w);
            accx = mix_acc_lo(accx, pu[1], e1w);
            accy = mix_acc_hi(accy, pu[1], e1w);
            accx = mix_acc_lo(accx, pu[2], e2w);
            accy = mix_acc_hi(accy, pu[2], e2w);
            accx = mix_acc_lo(accx, pu[3], e3w);
            accy = mix_acc_hi(accy, pu[3], e3w);
        }
    }
    // combine the two groups under a common basis M (factor cancels in normalize)
    float mo = __shfl_xor(m_run, 32, 64);
    float M  = fmaxf(m_run, mo);
    float cs = fexp2(m_run - M);
    accx *= cs; accy *= cs;
    accx += __shfl_xor(accx, 32, 64);
    accy += __shfl_xor(accy, 32, 64);
    float s2n = group_sum(accx * accx + accy * accy);
    float inv = 1.0f / fmaxf(sqrtf(s2n), EPS);
    if (hi) *(__half2*)&xh_new[w * DIM + 2 * gl] =
        __floats2half2_rn(accx * inv, accy * inv);
    // finalize for hops 2,3: unnormalized weights exp2(t2 - M), bounded by 2^THR2
    for (int i = beg + lane; i < end; i += 64)
        score[i] = fexp2(score[i] - M);
}

// hop2: x2 = norm(sum score*rel*x1[tail]); writes xh_new only.
__global__ void hop_kernel(const float* __restrict__ relemb,
                           const int2* __restrict__ rp2,
                           const int* __restrict__ packed,
                           const float* __restrict__ score,
                           const __half* __restrict__ xh_old,
                           __half* __restrict__ xh_new, int N, int R) {
    __shared__ unsigned srelh[1024];
    __shared__ __align__(16) int2 tile[4][64];
    for (int i = threadIdx.x; i < R * 32; i += blockDim.x) {
        float2 f = *(const float2*)&relemb[2 * i];
        __half2 h = __floats2half2_rn(f.x, f.y);
        srelh[i] = *reinterpret_cast<unsigned*>(&h);
    }
    __syncthreads();
    int w    = (blockIdx.x * blockDim.x + threadIdx.x) >> 6;
    int lane = threadIdx.x & 63;
    int wslot = (threadIdx.x >> 6) & 3;
    if (w >= N) return;
    int2 be = rp2[w];
    int beg = be.x, end = be.y;
    const int gl = lane & 31;
    const int gl4 = gl << 2;
    const int hi = lane >> 5;
    float accx = 0.f, accy = 0.f;
    for (int base = beg; base < end; base += 64) {
        int n = min(64, end - base);
        int2 ps = make_int2(0, 0);
        if (lane < n) {
            ps.x = packed[base + lane];
            ps.y = __float_as_int(score[base + lane]);
        }
        tile[wslot][lane] = ps;
        for (int j = 0; j < n; j += 16) {
            #pragma unroll
            for (int k = 0; k < 8; ++k) {
                int e0 = j + 2 * k;
                int4 q = *(const int4*)&tile[wslot][e0];
                int   pe = hi ? q.z : q.x;
                float se = __int_as_float(hi ? q.w : q.y);
                unsigned gu = gather_u(xh_old, pe, gl4);
                unsigned ru = srelh[((pe & 127) << 5) + gl];
                unsigned pu = pkmul_h2(ru, gu);
                accx = mix_acc_lo(accx, pu, se);
                accy = mix_acc_hi(accy, pu, se);
            }
        }
    }
    accx += __shfl_xor(accx, 32, 64);
    accy += __shfl_xor(accy, 32, 64);
    float s = group_sum(accx * accx + accy * accy);
    float inv = 1.0f / fmaxf(sqrtf(s), EPS);
    if (hi) *(__half2*)&xh_new[w * DIM + 2 * gl] =
        __floats2half2_rn(accx * inv, accy * inv);
}

// hop3: x3 from x2 gathers; out = ent + x1 + x2 + x3 (single coalesced write).
__global__ void hop3_kernel(const float* __restrict__ relemb,
                            const int2* __restrict__ rp2,
                            const int* __restrict__ packed,
                            const float* __restrict__ score,
                            const __half* __restrict__ xh2,
                            const __half* __restrict__ xh1,
                            const float* __restrict__ ent,
                            float* __restrict__ out, int N, int R) {
    __shared__ unsigned srelh[1024];
    __shared__ __align__(16) int2 tile[4][64];
    for (int i = threadIdx.x; i < R * 32; i += blockDim.x) {
        float2 f = *(const float2*)&relemb[2 * i];
        __half2 h = __floats2half2_rn(f.x, f.y);
        srelh[i] = *reinterpret_cast<unsigned*>(&h);
    }
    __syncthreads();
    int w    = (blockIdx.x * blockDim.x + threadIdx.x) >> 6;
    int lane = threadIdx.x & 63;
    int wslot = (threadIdx.x >> 6) & 3;
    if (w >= N) return;
    int2 be = rp2[w];
    int beg = be.x, end = be.y;
    const int gl = lane & 31;
    const int gl4 = gl << 2;
    const int hi = lane >> 5;
    float accx = 0.f, accy = 0.f;
    for (int base = beg; base < end; base += 64) {
        int n = min(64, end - base);
        int2 ps = make_int2(0, 0);
        if (lane < n) {
            ps.x = packed[base + lane];
            ps.y = __float_as_int(score[base + lane]);
        }
        tile[wslot][lane] = ps;
        for (int j = 0; j < n; j += 16) {
            #pragma unroll
            for (int k = 0; k < 8; ++k) {
                int e0 = j + 2 * k;
                int4 q = *(const int4*)&tile[wslot][e0];
                int   pe = hi ? q.z : q.x;
                float se = __int_as_float(hi ? q.w : q.y);
                unsigned gu = gather_u(xh2, pe, gl4);
                unsigned ru = srelh[((pe & 127) << 5) + gl];
                unsigned pu = pkmul_h2(ru, gu);
                accx = mix_acc_lo(accx, pu, se);
                accy = mix_acc_hi(accy, pu, se);
            }
        }
    }
    accx += __shfl_xor(accx, 32, 64);
    accy += __shfl_xor(accy, 32, 64);
    float s = group_sum(accx * accx + accy * accy);
    float inv = 1.0f / fmaxf(sqrtf(s), EPS);
    float xn0 = accx * inv, xn1 = accy * inv;
    if (hi == 0) {
        float2 ev = *(const float2*)&ent[w * DIM + 2 * gl];
        float2 f1 = __half22float2(*(const __half2*)&xh1[w * DIM + 2 * gl]);
        float2 f2 = __half22float2(*(const __half2*)&xh2[w * DIM + 2 * gl]);
        float2 o;
        o.x = ev.x + f1.x + f2.x + xn0;
        o.y = ev.y + f1.y + f2.y + xn1;
        *(float2*)&out[w * DIM + 2 * gl] = o;
    }
}

extern "C" void kernel_launch(void* const* d_in, const int* in_sizes, int n_in,
                              void* d_out, int out_size, void* d_ws, size_t ws_size,
                              hipStream_t stream) {
    const float* ent    = (const float*)d_in[0];
    const float* relemb = (const float*)d_in[1];
    const int*   eidx   = (const int*)d_in[2];
    const int*   etype  = (const int*)d_in[3];
    float* out = (float*)d_out;

    const int N = in_sizes[0] / DIM;   // 50000 (<= 65536 for 16-bit tail packing)
    const int R = in_sizes[1] / DIM;   // 20
    const int E = in_sizes[3];         // 800000
    const int* head = eidx;
    const int* tail = eidx + E;

    char* ws = (char*)d_ws;
    size_t off = 0;
    auto alloc = [&](size_t bytes) {
        char* p = ws + off;
        off += (bytes + 255) & ~size_t(255);
        return p;
    };
    int nbk = (N + 255) >> 8;                       // 256-node buckets (196)
    size_t padE = (size_t)nbk * CAPB;               // padded edge space
    int*   gcur   = (int*)alloc(256 * 4);
    int2*  rp2    = (int2*)alloc((size_t)N * 8);
    int*   bbuf   = (int*)alloc(padE * 4);
    int*   packed = (int*)alloc(padE * 4);
    float* score  = (float*)alloc(padE * 4);
    __half* xh0   = (__half*)alloc((size_t)N * DIM * 2);
    __half* xh1   = (__half*)alloc((size_t)N * DIM * 2);
    __half* xh2   = (__half*)alloc((size_t)N * DIM * 2);
    (void)ws_size;

    hipMemsetAsync(gcur, 0, 256 * 4, stream);

    // padded bucket-major CSR: pass1 (scatter + merged ent->fp16 init) -> pass2
    int ebBlocks = (E + BTILE - 1) / BTILE;
    int n4 = N * DIM / 4;
    bucket_pass1<<<ebBlocks, 256, 0, stream>>>(head, tail, etype, gcur, bbuf,
                                               (const float4*)ent, (ushort4*)xh0,
                                               n4, E);
    bucket_pass2<<<nbk, 256, 0, stream>>>(bbuf, gcur, rp2, packed, N);

    int nodeBlocks = (N + 3) / 4;   // 4 waves / block

    // fused: scores + hop1 (xh0 -> xh1) + exp2 finalize
    fused_score_hop1_kernel<<<nodeBlocks, 256, 0, stream>>>(xh0, relemb, rp2,
                                                            packed, score, xh1, N, R);
    // hop2 (xh1 -> xh2)
    hop_kernel<<<nodeBlocks, 256, 0, stream>>>(relemb, rp2, packed, score,
                                               xh1, xh2, N, R);
    // hop3: out = ent + x1 + x2 + x3
    hop3_kernel<<<nodeBlocks, 256, 0, stream>>>(relemb, rp2, packed, score,
                                                xh2, xh1, ent, out, N, R);
}